// Round 1
// baseline (935.996 us; speedup 1.0000x reference)
//
#include <hip/hip_runtime.h>

#define NN 100000
#define NSTEP 5

typedef unsigned short ushort_t;
typedef __attribute__((ext_vector_type(8))) short short8;
typedef __attribute__((ext_vector_type(4))) float floatx4;

__device__ __forceinline__ ushort_t f2bf(float f){
  union { float f; unsigned u; } v; v.f = f;
  unsigned r = v.u + 0x7fffu + ((v.u >> 16) & 1u);
  return (ushort_t)(r >> 16);
}
__device__ __forceinline__ float bf2f(ushort_t s){
  union { unsigned u; float f; } v; v.u = ((unsigned)s) << 16;
  return v.f;
}
__device__ __forceinline__ float sigf(float x){ return 1.0f/(1.0f+__expf(-x)); }

// ---------------- big GEMM: out(M,Nd) = act(A(M,K) @ BT(Nd,K)^T + bias) ----------------
// 4 waves/block in 2x2, each wave a 64x64 register tile of 16 16x16x32 MFMAs.
template<int A_FP32, int ACT, typename OutT>
__global__ __launch_bounds__(256) void gemm_big(const void* __restrict__ Ap,
    const ushort_t* __restrict__ BT, const float* __restrict__ bias,
    OutT* __restrict__ out, int M, int K, int Nd)
{
  int tid = threadIdx.x;
  int w = tid >> 6, lane = tid & 63;
  int qd = lane >> 4, r16 = lane & 15;
  int row0 = blockIdx.x*128 + (w & 1)*64;
  int col0 = blockIdx.y*128 + (w >> 1)*64;
  floatx4 acc[4][4];
  #pragma unroll
  for (int i=0;i<4;i++)
    #pragma unroll
    for(int j=0;j<4;j++) acc[i][j] = (floatx4){0.f,0.f,0.f,0.f};
  int rowi[4];
  #pragma unroll
  for (int i=0;i<4;i++){ int r = row0 + i*16 + r16; rowi[i] = r < M ? r : M-1; }

  for (int kk = 0; kk < K; kk += 32){
    int k = kk + qd*8;
    short8 af[4], bfr[4];
    #pragma unroll
    for (int i=0;i<4;i++){
      if constexpr (A_FP32){
        const float* A = (const float*)Ap;
        const float4* pp = (const float4*)(A + (size_t)rowi[i]*K + k);
        float4 x0 = pp[0], x1 = pp[1];
        short8 t;
        t[0]=(short)f2bf(x0.x); t[1]=(short)f2bf(x0.y); t[2]=(short)f2bf(x0.z); t[3]=(short)f2bf(x0.w);
        t[4]=(short)f2bf(x1.x); t[5]=(short)f2bf(x1.y); t[6]=(short)f2bf(x1.z); t[7]=(short)f2bf(x1.w);
        af[i] = t;
      } else {
        const ushort_t* A = (const ushort_t*)Ap;
        af[i] = *(const short8*)(A + (size_t)rowi[i]*K + k);
      }
    }
    #pragma unroll
    for (int j=0;j<4;j++)
      bfr[j] = *(const short8*)(BT + (size_t)(col0 + j*16 + r16)*K + k);
    #pragma unroll
    for (int i=0;i<4;i++)
      #pragma unroll
      for (int j=0;j<4;j++)
        acc[i][j] = __builtin_amdgcn_mfma_f32_16x16x32_bf16(af[i], bfr[j], acc[i][j], 0, 0, 0);
  }
  #pragma unroll
  for (int i=0;i<4;i++){
    int rbase = row0 + i*16 + qd*4;
    #pragma unroll
    for (int j=0;j<4;j++){
      int col = col0 + j*16 + r16;
      float bb = bias[col];
      #pragma unroll
      for (int rr=0;rr<4;rr++){
        int r_ = rbase + rr;
        if (r_ < M){
          float v = acc[i][j][rr] + bb;
          if (ACT == 1) v = v > 0.f ? v : expm1f(v);
          if constexpr (sizeof(OutT) == 2) out[(size_t)r_*Nd + col] = (OutT)f2bf(v);
          else                             out[(size_t)r_*Nd + col] = v;
        }
      }
    }
  }
}

// ---------------- small GEMM for LSTM gates: gates(128,1024) = A(128,K) @ BT(1024,K)^T + bc ----------
// one wave per 16x16 tile, 512 single-wave blocks
__global__ __launch_bounds__(64) void gemm_small(const ushort_t* __restrict__ A,
    const ushort_t* __restrict__ BT, const float* __restrict__ bc,
    float* __restrict__ gates, int K)
{
  int t = blockIdx.x;
  int m0 = (t & 7) * 16, n0 = (t >> 3) * 16;
  int lane = threadIdx.x, qd = lane >> 4, r16 = lane & 15;
  const ushort_t* Ar = A + (size_t)(m0 + r16)*K + qd*8;
  const ushort_t* Br = BT + (size_t)(n0 + r16)*K + qd*8;
  floatx4 acc = (floatx4){0.f,0.f,0.f,0.f};
  for (int kk = 0; kk < K; kk += 64){
    short8 a0 = *(const short8*)(Ar + kk);
    short8 b0 = *(const short8*)(Br + kk);
    short8 a1 = *(const short8*)(Ar + kk + 32);
    short8 b1 = *(const short8*)(Br + kk + 32);
    acc = __builtin_amdgcn_mfma_f32_16x16x32_bf16(a0, b0, acc, 0, 0, 0);
    acc = __builtin_amdgcn_mfma_f32_16x16x32_bf16(a1, b1, acc, 0, 0, 0);
  }
  int col = n0 + r16;
  float bb = bc[col];
  #pragma unroll
  for (int rr=0;rr<4;rr++)
    gates[(m0 + qd*4 + rr)*1024 + col] = acc[rr] + bb;
}

// ---------------- LSTM cell pointwise; writes h as bf16 into two concat-input slots ----------------
__global__ __launch_bounds__(256) void cell_k(const float* __restrict__ gates, float* __restrict__ c,
    ushort_t* __restrict__ dstA, int strideA, ushort_t* __restrict__ dstB, int strideB,
    float* __restrict__ qdst)
{
  int b = blockIdx.x, h = threadIdx.x;
  const float* g = gates + b*1024;
  float gi = g[h], gf = g[h+256], gg = g[h+512], go = g[h+768];
  float cp = c[b*256 + h];
  float cn = sigf(gf)*cp + sigf(gi)*tanhf(gg);
  float hn = sigf(go)*tanhf(cn);
  c[b*256 + h] = cn;
  ushort_t hb = f2bf(hn);
  dstA[b*strideA + h] = hb;
  dstB[b*strideB + h] = hb;
  if (qdst) qdst[b*512 + h] = hn;
}

// ---------------- attention: e[n] = dot(hfeat[n], q[batch[n]]); wave per node ----------------
__global__ __launch_bounds__(256) void attn_e(const float* __restrict__ hfeat,
    const float* __restrict__ q_star, const int* __restrict__ bidx, float* __restrict__ e)
{
  int node = blockIdx.x*4 + (threadIdx.x >> 6);
  int lane = threadIdx.x & 63;
  int b = bidx[node];
  float4 hv = *(const float4*)(hfeat + (size_t)node*256 + lane*4);
  float4 qv = *(const float4*)(q_star + (size_t)b*512 + lane*4);
  float s = hv.x*qv.x + hv.y*qv.y + hv.z*qv.z + hv.w*qv.w;
  #pragma unroll
  for (int off = 32; off; off >>= 1) s += __shfl_xor(s, off);
  if (lane == 0) e[node] = s;
}

// ---------------- segment softmax: block per segment ----------------
__global__ __launch_bounds__(256) void attn_soft(const float* __restrict__ e,
    const int* __restrict__ seg, float* __restrict__ a)
{
  int b = blockIdx.x;
  int s = seg[b], en = seg[b+1];
  if (s >= en) return;
  int tid = threadIdx.x, lane = tid & 63, wid = tid >> 6;
  __shared__ float sm[4];
  __shared__ float bcast;
  float m = -INFINITY;
  for (int i = s + tid; i < en; i += 256) m = fmaxf(m, e[i]);
  #pragma unroll
  for (int off = 32; off; off >>= 1) m = fmaxf(m, __shfl_xor(m, off));
  if (lane == 0) sm[wid] = m;
  __syncthreads();
  if (tid == 0) bcast = fmaxf(fmaxf(sm[0], sm[1]), fmaxf(sm[2], sm[3]));
  __syncthreads();
  m = bcast;
  __syncthreads();
  float sum = 0.f;
  for (int i = s + tid; i < en; i += 256){ float ex = expf(e[i] - m); a[i] = ex; sum += ex; }
  #pragma unroll
  for (int off = 32; off; off >>= 1) sum += __shfl_xor(sum, off);
  if (lane == 0) sm[wid] = sum;
  __syncthreads();
  if (tid == 0) bcast = 1.0f / (sm[0] + sm[1] + sm[2] + sm[3] + 1e-16f);
  __syncthreads();
  float inv = bcast;
  for (int i = s + tid; i < en; i += 256) a[i] *= inv;
}

// ---------------- r[b] = sum a[n]*hfeat[n]; block per segment, feature per thread ----------------
__global__ __launch_bounds__(256) void attn_r(const float* __restrict__ hfeat,
    const float* __restrict__ a, const int* __restrict__ seg,
    float* __restrict__ q_star, ushort_t* __restrict__ xc0)
{
  int b = blockIdx.x, tid = threadIdx.x;
  int s = seg[b], en = seg[b+1];
  float acc = 0.f;
  int n = s;
  for (; n + 4 <= en; n += 4){
    float a0 = a[n], a1 = a[n+1], a2 = a[n+2], a3 = a[n+3];
    float h0 = hfeat[(size_t)n*256 + tid];
    float h1 = hfeat[(size_t)(n+1)*256 + tid];
    float h2 = hfeat[(size_t)(n+2)*256 + tid];
    float h3 = hfeat[(size_t)(n+3)*256 + tid];
    acc += a0*h0 + a1*h1 + a2*h2 + a3*h3;
  }
  for (; n < en; n++) acc += a[n] * hfeat[(size_t)n*256 + tid];
  q_star[b*512 + 256 + tid] = acc;
  xc0[b*768 + 256 + tid] = f2bf(acc);
}

// ---------------- final: out(128,128) = q_star(128,512) @ outW(512,128) + outb ----------------
__global__ __launch_bounds__(128) void final_k(const float* __restrict__ q_star,
    const float* __restrict__ W, const float* __restrict__ bias, float* __restrict__ out)
{
  __shared__ float qs[512];
  int b = blockIdx.x, e = threadIdx.x;
  #pragma unroll
  for (int i = 0; i < 4; i++) qs[e + i*128] = q_star[b*512 + e + i*128];
  __syncthreads();
  float acc = bias[e];
  for (int k = 0; k < 512; k++) acc += qs[k] * W[k*128 + e];
  out[b*128 + e] = acc;
}

// ---------------- prep: weight bf16 conversion/packing ----------------
__global__ void prep_w(const float* __restrict__ W1, const float* __restrict__ W2,
    const float* __restrict__ Wih0, const float* __restrict__ Whh0,
    const float* __restrict__ Wih1, const float* __restrict__ Whh1,
    const float* __restrict__ Wih2, const float* __restrict__ Whh2,
    ushort_t* __restrict__ W1T, ushort_t* __restrict__ W2T,
    ushort_t* __restrict__ Wc0, ushort_t* __restrict__ Wc1, ushort_t* __restrict__ Wc2)
{
  int i = blockIdx.x*256 + threadIdx.x;
  if (i < 65536){                       // W1T[n,k] = W1[k,n]
    W1T[i] = f2bf(W1[(i & 255)*256 + (i >> 8)]);
  } else if (i < 131072){
    int j = i - 65536;
    W2T[j] = f2bf(W2[(j & 255)*256 + (j >> 8)]);
  } else if (i < 131072 + 786432){      // Wc0[g, 0:512]=Wih0, [512:768]=Whh0
    int j = i - 131072;
    int g = j / 768, k = j - g*768;
    Wc0[j] = f2bf(k < 512 ? Wih0[g*512 + k] : Whh0[g*256 + (k - 512)]);
  } else if (i < 131072 + 786432 + 524288){
    int j = i - (131072 + 786432);
    int g = j >> 9, k = j & 511;
    Wc1[j] = f2bf(k < 256 ? Wih1[g*256 + k] : Whh1[g*256 + (k - 256)]);
  } else if (i < 131072 + 786432 + 1048576){
    int j = i - (131072 + 786432 + 524288);
    int g = j >> 9, k = j & 511;
    Wc2[j] = f2bf(k < 256 ? Wih2[g*256 + k] : Whh2[g*256 + (k - 256)]);
  }
}

// ---------------- prep: zeros + combined biases + segment bounds ----------------
__global__ void prep_misc(const float* __restrict__ bih0, const float* __restrict__ bhh0,
    const float* __restrict__ bih1, const float* __restrict__ bhh1,
    const float* __restrict__ bih2, const float* __restrict__ bhh2,
    const int* __restrict__ bidx,
    float* __restrict__ c, ushort_t* __restrict__ xc, float* __restrict__ q_star,
    float* __restrict__ bc, int* __restrict__ seg)
{
  int i = blockIdx.x*256 + threadIdx.x;
  if (i < 98304) { c[i] = 0.f; return; }
  i -= 98304;
  if (i < 229376) { xc[i] = 0; return; }
  i -= 229376;
  if (i < 65536) { q_star[i] = 0.f; return; }
  i -= 65536;
  if (i < 3072) {
    int l = i >> 10, g = i & 1023;
    const float* bi = (l == 0) ? bih0 : ((l == 1) ? bih1 : bih2);
    const float* bh = (l == 0) ? bhh0 : ((l == 1) ? bhh1 : bhh2);
    bc[i] = bi[g] + bh[g];
    return;
  }
  i -= 3072;
  if (i < 129) {
    int lo = 0, hi = NN;
    while (lo < hi){ int mid = (lo + hi) >> 1; if (bidx[mid] < i) lo = mid + 1; else hi = mid; }
    seg[i] = lo;
  }
}

extern "C" void kernel_launch(void* const* d_in, const int* in_sizes, int n_in,
                              void* d_out, int out_size, void* d_ws, size_t ws_size,
                              hipStream_t stream)
{
  const float* x    = (const float*)d_in[0];
  const int*   bidx = (const int*)  d_in[1];
  const float* W1   = (const float*)d_in[2];
  const float* b1   = (const float*)d_in[3];
  const float* W2   = (const float*)d_in[4];
  const float* b2   = (const float*)d_in[5];
  const float* Wih0 = (const float*)d_in[6];
  const float* Whh0 = (const float*)d_in[7];
  const float* bih0 = (const float*)d_in[8];
  const float* bhh0 = (const float*)d_in[9];
  const float* Wih1 = (const float*)d_in[10];
  const float* Whh1 = (const float*)d_in[11];
  const float* bih1 = (const float*)d_in[12];
  const float* bhh1 = (const float*)d_in[13];
  const float* Wih2 = (const float*)d_in[14];
  const float* Whh2 = (const float*)d_in[15];
  const float* bih2 = (const float*)d_in[16];
  const float* bhh2 = (const float*)d_in[17];
  const float* outW = (const float*)d_in[18];
  const float* outb = (const float*)d_in[19];

  char* p = (char*)d_ws;
  auto alloc = [&](size_t bytes)->char*{ char* r = p; p += (bytes + 255) & ~(size_t)255; return r; };
  ushort_t* t_bf   = (ushort_t*)alloc((size_t)NN*256*2);   // FNN intermediate, bf16
  float*    hfeat  = (float*)   alloc((size_t)NN*256*4);   // fp32 node features
  float*    e_ws   = (float*)   alloc((size_t)NN*4);
  float*    a_ws   = (float*)   alloc((size_t)NN*4);
  ushort_t* W1T    = (ushort_t*)alloc(65536*2);
  ushort_t* W2T    = (ushort_t*)alloc(65536*2);
  ushort_t* Wc0    = (ushort_t*)alloc(786432*2);
  ushort_t* Wc1    = (ushort_t*)alloc(524288*2);
  ushort_t* Wc2    = (ushort_t*)alloc(524288*2);
  float*    bc     = (float*)   alloc(3072*4);
  float*    c_all  = (float*)   alloc(98304*4);
  ushort_t* xc     = (ushort_t*)alloc(229376*2);           // xc0(128x768) | xc1(128x512) | xc2(128x512)
  float*    q_star = (float*)   alloc(65536*4);            // (128, 512) fp32
  float*    gates  = (float*)   alloc(131072*4);           // (128, 1024) fp32
  int*      seg    = (int*)     alloc(129*4);

  ushort_t* xc0 = xc;
  ushort_t* xc1 = xc + 98304;
  ushort_t* xc2 = xc + 163840;
  float* c0 = c_all, *c1 = c_all + 32768, *c2 = c_all + 65536;
  float* bc0 = bc, *bc1 = bc + 1024, *bc2 = bc + 2048;

  prep_w<<<7680, 256, 0, stream>>>(W1, W2, Wih0, Whh0, Wih1, Whh1, Wih2, Whh2,
                                   W1T, W2T, Wc0, Wc1, Wc2);
  prep_misc<<<1549, 256, 0, stream>>>(bih0, bhh0, bih1, bhh1, bih2, bhh2, bidx,
                                      c_all, xc, q_star, bc, seg);

  // FNN: t = elu(x@W1+b1) [bf16]; hfeat = t@W2+b2 [fp32]
  gemm_big<1, 1, ushort_t><<<dim3(782, 2), 256, 0, stream>>>(x, W1T, b1, t_bf, NN, 256, 256);
  gemm_big<0, 0, float>   <<<dim3(782, 2), 256, 0, stream>>>(t_bf, W2T, b2, hfeat, NN, 256, 256);

  for (int s = 0; s < NSTEP; s++){
    // layer 0: in = [q_star | h0_prev] (K=768)
    gemm_small<<<512, 64, 0, stream>>>(xc0, Wc0, bc0, gates, 768);
    cell_k<<<128, 256, 0, stream>>>(gates, c0, xc0 + 512, 768, xc1, 512, nullptr);
    // layer 1: in = [h0 | h1_prev] (K=512)
    gemm_small<<<512, 64, 0, stream>>>(xc1, Wc1, bc1, gates, 512);
    cell_k<<<128, 256, 0, stream>>>(gates, c1, xc1 + 256, 512, xc2, 512, nullptr);
    // layer 2: in = [h1 | h2_prev] (K=512); h2 = q -> q_star[:, :256] fp32 + xc0[:, :256] bf16
    gemm_small<<<512, 64, 0, stream>>>(xc2, Wc2, bc2, gates, 512);
    cell_k<<<128, 256, 0, stream>>>(gates, c2, xc2 + 256, 512, xc0, 768, q_star);
    // attention
    attn_e<<<NN/4, 256, 0, stream>>>(hfeat, q_star, bidx, e_ws);
    attn_soft<<<128, 256, 0, stream>>>(e_ws, seg, a_ws);
    attn_r<<<128, 256, 0, stream>>>(hfeat, a_ws, seg, q_star, xc0);
  }

  final_k<<<128, 128, 0, stream>>>(q_star, outW, outb, (float*)d_out);
}

// Round 3
// 888.111 us; speedup vs baseline: 1.0539x; 1.0539x over previous
//
#include <hip/hip_runtime.h>

#define NN 100000
#define NSTEP 5
#define LSTR 260   // LDS row stride (ushorts) for 64x256 tiles: 520B rows, bank coeff 2

typedef unsigned short ushort_t;
typedef __attribute__((ext_vector_type(8))) short short8;
typedef __attribute__((ext_vector_type(4))) short short4_t;
typedef __attribute__((ext_vector_type(4))) float floatx4;

union S8u { short8 v; struct { short4_t lo; short4_t hi; } p; };

__device__ __forceinline__ ushort_t f2bf(float f){
  union { float f; unsigned u; } v; v.f = f;
  unsigned r = v.u + 0x7fffu + ((v.u >> 16) & 1u);
  return (ushort_t)(r >> 16);
}
__device__ __forceinline__ float bf2f(ushort_t s){
  union { unsigned u; float f; } v; v.u = ((unsigned)s) << 16;
  return v.f;
}
__device__ __forceinline__ float sigf(float x){ return 1.0f/(1.0f+__expf(-x)); }

// ================= fused FNN: hfeat = (elu(x@W1+b1))@W2+b2, bf16 out =================
// block = 256 thr (4 waves), 64 rows x 256 cols. x tile staged bf16 in LDS; t tile
// reuses the same LDS buffer. Each wave owns a 64x64 output strip (wave w -> cols w*64).
__global__ __launch_bounds__(256, 3) void fnn_fused(const float* __restrict__ x,
    const ushort_t* __restrict__ W1T, const float* __restrict__ b1,
    const ushort_t* __restrict__ W2T, const float* __restrict__ b2,
    ushort_t* __restrict__ hfeat, int M)
{
  __shared__ ushort_t buf[64 * LSTR];
  int tid = threadIdx.x;
  int w = tid >> 6, lane = tid & 63, qd = lane >> 4, r16 = lane & 15;
  int row0 = blockIdx.x * 64;
  int col0 = w * 64;

  // ---- stage x tile (64x256 fp32 -> bf16 LDS): 4 threads/row x 16 float4 chunks ----
  {
    int r = tid >> 2;
    int rg = row0 + r; if (rg >= M) rg = M - 1;
    const float* src = x + (size_t)rg * 256;
    #pragma unroll
    for (int i = 0; i < 16; i++){
      int c = (tid & 3) * 4 + i * 16;          // float col index: covers 0..252
      float4 v = *(const float4*)(src + c);
      ushort4 pk = make_ushort4(f2bf(v.x), f2bf(v.y), f2bf(v.z), f2bf(v.w));
      *(ushort4*)&buf[r * LSTR + c] = pk;
    }
  }
  __syncthreads();

  // ---- GEMM1: t = x @ W1T^T ----
  floatx4 acc[4][4];
  #pragma unroll
  for (int i=0;i<4;i++)
    #pragma unroll
    for (int j=0;j<4;j++) acc[i][j] = (floatx4){0.f,0.f,0.f,0.f};

  for (int kk = 0; kk < 256; kk += 32){
    int k = kk + qd * 8;
    short8 af[4], bfr[4];
    #pragma unroll
    for (int i = 0; i < 4; i++){
      const ushort_t* pa = &buf[(i*16 + r16) * LSTR + k];
      S8u u; u.p.lo = *(const short4_t*)pa; u.p.hi = *(const short4_t*)(pa + 4);
      af[i] = u.v;
    }
    #pragma unroll
    for (int j = 0; j < 4; j++)
      bfr[j] = *(const short8*)(W1T + (size_t)(col0 + j*16 + r16) * 256 + k);
    #pragma unroll
    for (int i=0;i<4;i++)
      #pragma unroll
      for (int j=0;j<4;j++)
        acc[i][j] = __builtin_amdgcn_mfma_f32_16x16x32_bf16(af[i], bfr[j], acc[i][j], 0, 0, 0);
  }
  __syncthreads();

  // ---- ELU + bf16 -> t tile in same LDS buffer ----
  #pragma unroll
  for (int i=0;i<4;i++){
    #pragma unroll
    for (int j=0;j<4;j++){
      int col = col0 + j*16 + r16;
      float bb = b1[col];
      #pragma unroll
      for (int rr=0;rr<4;rr++){
        int row = i*16 + qd*4 + rr;
        float v = acc[i][j][rr] + bb;
        v = v > 0.f ? v : expm1f(v);
        buf[row * LSTR + col] = f2bf(v);
      }
    }
  }
  __syncthreads();

  // ---- GEMM2: hfeat = t @ W2T^T ----
  floatx4 acc2[4][4];
  #pragma unroll
  for (int i=0;i<4;i++)
    #pragma unroll
    for (int j=0;j<4;j++) acc2[i][j] = (floatx4){0.f,0.f,0.f,0.f};

  for (int kk = 0; kk < 256; kk += 32){
    int k = kk + qd * 8;
    short8 af[4], bfr[4];
    #pragma unroll
    for (int i = 0; i < 4; i++){
      const ushort_t* pa = &buf[(i*16 + r16) * LSTR + k];
      S8u u; u.p.lo = *(const short4_t*)pa; u.p.hi = *(const short4_t*)(pa + 4);
      af[i] = u.v;
    }
    #pragma unroll
    for (int j = 0; j < 4; j++)
      bfr[j] = *(const short8*)(W2T + (size_t)(col0 + j*16 + r16) * 256 + k);
    #pragma unroll
    for (int i=0;i<4;i++)
      #pragma unroll
      for (int j=0;j<4;j++)
        acc2[i][j] = __builtin_amdgcn_mfma_f32_16x16x32_bf16(af[i], bfr[j], acc2[i][j], 0, 0, 0);
  }

  // ---- epilogue: bf16 store ----
  #pragma unroll
  for (int i=0;i<4;i++){
    #pragma unroll
    for (int j=0;j<4;j++){
      int col = col0 + j*16 + r16;
      float bb = b2[col];
      #pragma unroll
      for (int rr=0;rr<4;rr++){
        int row = row0 + i*16 + qd*4 + rr;
        if (row < M) hfeat[(size_t)row * 256 + col] = f2bf(acc2[i][j][rr] + bb);
      }
    }
  }
}

// ================= fused LSTM layer: gates GEMM (K-split x4) + cell pointwise =================
// grid 128 blocks x 4 waves. Block: 16 rows (m0) x 16 h (n0) x 4 gates. Wave w does K/4.
__global__ __launch_bounds__(256) void lstm_layer(const ushort_t* __restrict__ A, int lda,
    const ushort_t* __restrict__ Wc, const float* __restrict__ bc, int K,
    float* __restrict__ c, ushort_t* __restrict__ dstA, int sA,
    ushort_t* __restrict__ dstB, int sB, float* __restrict__ qdst)
{
  __shared__ float sbuf[3][4][256];
  int tid = threadIdx.x, w = tid >> 6, lane = tid & 63, qd = lane >> 4, r16 = lane & 15;
  int m0 = (blockIdx.x & 7) * 16, n0 = (blockIdx.x >> 3) * 16;
  int kq = K >> 2;
  int kbeg = w * kq, kend = kbeg + kq;

  floatx4 acc[4];
  #pragma unroll
  for (int g=0; g<4; g++) acc[g] = (floatx4){0.f,0.f,0.f,0.f};

  const ushort_t* Ar = A + (size_t)(m0 + r16) * lda + qd * 8;
  for (int kk = kbeg; kk < kend; kk += 32){
    short8 av = *(const short8*)(Ar + kk);
    #pragma unroll
    for (int g = 0; g < 4; g++){
      short8 bv = *(const short8*)(Wc + (size_t)(g*256 + n0 + r16) * K + kk + qd*8);
      acc[g] = __builtin_amdgcn_mfma_f32_16x16x32_bf16(av, bv, acc[g], 0, 0, 0);
    }
  }

  if (w){
    #pragma unroll
    for (int g=0; g<4; g++) *(floatx4*)&sbuf[w-1][g][lane*4] = acc[g];
  }
  __syncthreads();
  if (w == 0){
    #pragma unroll
    for (int g=0; g<4; g++)
      #pragma unroll
      for (int t=0; t<3; t++){
        floatx4 p = *(floatx4*)&sbuf[t][g][lane*4];
        acc[g][0]+=p[0]; acc[g][1]+=p[1]; acc[g][2]+=p[2]; acc[g][3]+=p[3];
      }
    int h = n0 + r16;
    float bci = bc[h], bcf = bc[256+h], bcg = bc[512+h], bco = bc[768+h];
    #pragma unroll
    for (int rr=0; rr<4; rr++){
      int row = m0 + qd*4 + rr;
      float gi = acc[0][rr] + bci;
      float gf = acc[1][rr] + bcf;
      float gg = acc[2][rr] + bcg;
      float go = acc[3][rr] + bco;
      float cp = c[row*256 + h];
      float cn = sigf(gf)*cp + sigf(gi)*tanhf(gg);
      float hn = sigf(go)*tanhf(cn);
      c[row*256 + h] = cn;
      ushort_t hb = f2bf(hn);
      dstA[row*sA + h] = hb;
      dstB[row*sB + h] = hb;
      if (qdst) qdst[row*512 + h] = hn;
    }
  }
}

// ================= attention: e[n] = dot(hfeat[n], q[batch[n]]) =================
__global__ __launch_bounds__(256) void attn_e(const ushort_t* __restrict__ hfeat,
    const float* __restrict__ q_star, const int* __restrict__ bidx, float* __restrict__ e)
{
  int node = blockIdx.x*4 + (threadIdx.x >> 6);
  int lane = threadIdx.x & 63;
  int b = bidx[node];
  ushort4 hv = *(const ushort4*)(hfeat + (size_t)node*256 + lane*4);
  float4 qv = *(const float4*)(q_star + (size_t)b*512 + lane*4);
  float s = bf2f(hv.x)*qv.x + bf2f(hv.y)*qv.y + bf2f(hv.z)*qv.z + bf2f(hv.w)*qv.w;
  #pragma unroll
  for (int off = 32; off; off >>= 1) s += __shfl_xor(s, off);
  if (lane == 0) e[node] = s;
}

// ================= segment softmax: a[i] = exp(e-m)/sum; also zero r =================
__global__ __launch_bounds__(256) void attn_ms(const float* __restrict__ e,
    const int* __restrict__ seg, float* __restrict__ a, float* __restrict__ r)
{
  int b = blockIdx.x, tid = threadIdx.x, lane = tid & 63, wid = tid >> 6;
  r[b*256 + tid] = 0.f;
  int s = seg[b], en = seg[b+1];
  if (s >= en) return;
  __shared__ float sm[4];
  __shared__ float bc_;
  float m = -INFINITY;
  for (int i = s + tid; i < en; i += 256) m = fmaxf(m, e[i]);
  #pragma unroll
  for (int off = 32; off; off >>= 1) m = fmaxf(m, __shfl_xor(m, off));
  if (lane == 0) sm[wid] = m;
  __syncthreads();
  if (tid == 0) bc_ = fmaxf(fmaxf(sm[0], sm[1]), fmaxf(sm[2], sm[3]));
  __syncthreads();
  m = bc_;
  float sum = 0.f;
  for (int i = s + tid; i < en; i += 256) sum += __expf(e[i] - m);
  #pragma unroll
  for (int off = 32; off; off >>= 1) sum += __shfl_xor(sum, off);
  if (lane == 0) sm[wid] = sum;
  __syncthreads();
  if (tid == 0) bc_ = 1.0f / (sm[0] + sm[1] + sm[2] + sm[3] + 1e-16f);
  __syncthreads();
  float inv = bc_;
  for (int i = s + tid; i < en; i += 256) a[i] = __expf(e[i] - m) * inv;
}

// ================= r[b] += sum a[n]*hfeat[n]; node-parallel, atomic flush =================
__global__ __launch_bounds__(256) void attn_r(const ushort_t* __restrict__ hfeat,
    const float* __restrict__ a, const int* __restrict__ bidx, float* __restrict__ r)
{
  int n0 = blockIdx.x * 256, f = threadIdx.x;
  int nend = n0 + 256; if (nend > NN) nend = NN;
  int bcur = bidx[n0];
  float acc = 0.f;
  for (int n = n0; n < nend; n++){
    int b = bidx[n];
    if (b != bcur){
      atomicAdd(&r[bcur*256 + f], acc);
      acc = 0.f; bcur = b;
    }
    acc += a[n] * bf2f(hfeat[(size_t)n*256 + f]);
  }
  atomicAdd(&r[bcur*256 + f], acc);
}

// ================= finalize r -> q_star[:,256:] fp32 + xc0[:,256:512] bf16 =================
__global__ __launch_bounds__(256) void attn_fin(const float* __restrict__ r,
    float* __restrict__ q_star, ushort_t* __restrict__ xc0)
{
  int b = blockIdx.x, f = threadIdx.x;
  float v = r[b*256 + f];
  q_star[b*512 + 256 + f] = v;
  xc0[b*768 + 256 + f] = f2bf(v);
}

// ================= final: out(128,128) = q_star(128,512) @ outW + outb =================
__global__ __launch_bounds__(128) void final_k(const float* __restrict__ q_star,
    const float* __restrict__ W, const float* __restrict__ bias, float* __restrict__ out)
{
  __shared__ float qs[512];
  int b = blockIdx.x, e = threadIdx.x;
  #pragma unroll
  for (int i = 0; i < 4; i++) qs[e + i*128] = q_star[b*512 + e + i*128];
  __syncthreads();
  float acc = bias[e];
  for (int k = 0; k < 512; k++) acc += qs[k] * W[k*128 + e];
  out[b*128 + e] = acc;
}

// ================= prep: weight bf16 conversion/packing =================
__global__ void prep_w(const float* __restrict__ W1, const float* __restrict__ W2,
    const float* __restrict__ Wih0, const float* __restrict__ Whh0,
    const float* __restrict__ Wih1, const float* __restrict__ Whh1,
    const float* __restrict__ Wih2, const float* __restrict__ Whh2,
    ushort_t* __restrict__ W1T, ushort_t* __restrict__ W2T,
    ushort_t* __restrict__ Wc0, ushort_t* __restrict__ Wc1, ushort_t* __restrict__ Wc2)
{
  int i = blockIdx.x*256 + threadIdx.x;
  if (i < 65536){                       // W1T[n,k] = W1[k,n]
    W1T[i] = f2bf(W1[(i & 255)*256 + (i >> 8)]);
  } else if (i < 131072){
    int j = i - 65536;
    W2T[j] = f2bf(W2[(j & 255)*256 + (j >> 8)]);
  } else if (i < 131072 + 786432){      // Wc0[g, 0:512]=Wih0, [512:768]=Whh0
    int j = i - 131072;
    int g = j / 768, k = j - g*768;
    Wc0[j] = f2bf(k < 512 ? Wih0[g*512 + k] : Whh0[g*256 + (k - 512)]);
  } else if (i < 131072 + 786432 + 524288){
    int j = i - (131072 + 786432);
    int g = j >> 9, k = j & 511;
    Wc1[j] = f2bf(k < 256 ? Wih1[g*256 + k] : Whh1[g*256 + (k - 256)]);
  } else if (i < 131072 + 786432 + 1048576){
    int j = i - (131072 + 786432 + 524288);
    int g = j >> 9, k = j & 511;
    Wc2[j] = f2bf(k < 256 ? Wih2[g*256 + k] : Whh2[g*256 + (k - 256)]);
  }
}

// ================= prep: zeros + combined biases + segment bounds =================
__global__ void prep_misc(const float* __restrict__ bih0, const float* __restrict__ bhh0,
    const float* __restrict__ bih1, const float* __restrict__ bhh1,
    const float* __restrict__ bih2, const float* __restrict__ bhh2,
    const int* __restrict__ bidx,
    float* __restrict__ c, ushort_t* __restrict__ xc, float* __restrict__ q_star,
    float* __restrict__ bc, int* __restrict__ seg)
{
  int i = blockIdx.x*256 + threadIdx.x;
  if (i < 98304) { c[i] = 0.f; return; }
  i -= 98304;
  if (i < 229376) { xc[i] = 0; return; }
  i -= 229376;
  if (i < 65536) { q_star[i] = 0.f; return; }
  i -= 65536;
  if (i < 3072) {
    int l = i >> 10, g = i & 1023;
    const float* bi = (l == 0) ? bih0 : ((l == 1) ? bih1 : bih2);
    const float* bh = (l == 0) ? bhh0 : ((l == 1) ? bhh1 : bhh2);
    bc[i] = bi[g] + bh[g];
    return;
  }
  i -= 3072;
  if (i < 129) {
    int lo = 0, hi = NN;
    while (lo < hi){ int mid = (lo + hi) >> 1; if (bidx[mid] < i) lo = mid + 1; else hi = mid; }
    seg[i] = lo;
  }
}

extern "C" void kernel_launch(void* const* d_in, const int* in_sizes, int n_in,
                              void* d_out, int out_size, void* d_ws, size_t ws_size,
                              hipStream_t stream)
{
  const float* x    = (const float*)d_in[0];
  const int*   bidx = (const int*)  d_in[1];
  const float* W1   = (const float*)d_in[2];
  const float* b1   = (const float*)d_in[3];
  const float* W2   = (const float*)d_in[4];
  const float* b2   = (const float*)d_in[5];
  const float* Wih0 = (const float*)d_in[6];
  const float* Whh0 = (const float*)d_in[7];
  const float* bih0 = (const float*)d_in[8];
  const float* bhh0 = (const float*)d_in[9];
  const float* Wih1 = (const float*)d_in[10];
  const float* Whh1 = (const float*)d_in[11];
  const float* bih1 = (const float*)d_in[12];
  const float* bhh1 = (const float*)d_in[13];
  const float* Wih2 = (const float*)d_in[14];
  const float* Whh2 = (const float*)d_in[15];
  const float* bih2 = (const float*)d_in[16];
  const float* bhh2 = (const float*)d_in[17];
  const float* outW = (const float*)d_in[18];
  const float* outb = (const float*)d_in[19];

  char* p = (char*)d_ws;
  auto alloc = [&](size_t bytes)->char*{ char* r = p; p += (bytes + 255) & ~(size_t)255; return r; };
  ushort_t* hfeat  = (ushort_t*)alloc((size_t)NN*256*2);   // bf16 node features
  float*    e_ws   = (float*)   alloc((size_t)NN*4);
  float*    a_ws   = (float*)   alloc((size_t)NN*4);
  ushort_t* W1T    = (ushort_t*)alloc(65536*2);
  ushort_t* W2T    = (ushort_t*)alloc(65536*2);
  ushort_t* Wc0    = (ushort_t*)alloc(786432*2);
  ushort_t* Wc1    = (ushort_t*)alloc(524288*2);
  ushort_t* Wc2    = (ushort_t*)alloc(524288*2);
  float*    bc     = (float*)   alloc(3072*4);
  float*    c_all  = (float*)   alloc(98304*4);
  ushort_t* xc     = (ushort_t*)alloc(229376*2);           // xc0(128x768) | xc1(128x512) | xc2(128x512)
  float*    q_star = (float*)   alloc(65536*4);            // (128, 512) fp32
  float*    r_ws   = (float*)   alloc(32768*4);            // (128, 256) fp32
  int*      seg    = (int*)     alloc(129*4);

  ushort_t* xc0 = xc;
  ushort_t* xc1 = xc + 98304;
  ushort_t* xc2 = xc + 163840;
  float* c0 = c_all, *c1 = c_all + 32768, *c2 = c_all + 65536;
  float* bc0 = bc, *bc1 = bc + 1024, *bc2 = bc + 2048;

  prep_w<<<7680, 256, 0, stream>>>(W1, W2, Wih0, Whh0, Wih1, Whh1, Wih2, Whh2,
                                   W1T, W2T, Wc0, Wc1, Wc2);
  prep_misc<<<1549, 256, 0, stream>>>(bih0, bhh0, bih1, bhh1, bih2, bhh2, bidx,
                                      c_all, xc, q_star, bc, seg);

  fnn_fused<<<1563, 256, 0, stream>>>(x, W1T, b1, W2T, b2, hfeat, NN);

  for (int s = 0; s < NSTEP; s++){
    // layer 0: in = [q_star | h0_prev] (K=768)
    lstm_layer<<<128, 256, 0, stream>>>(xc0, 768, Wc0, bc0, 768, c0, xc0 + 512, 768, xc1, 512, nullptr);
    // layer 1: in = [h0 | h1_prev] (K=512)
    lstm_layer<<<128, 256, 0, stream>>>(xc1, 512, Wc1, bc1, 512, c1, xc1 + 256, 512, xc2, 512, nullptr);
    // layer 2: in = [h1 | h2_prev] (K=512); h2 = q
    lstm_layer<<<128, 256, 0, stream>>>(xc2, 512, Wc2, bc2, 512, c2, xc2 + 256, 512, xc0, 768, q_star);
    // attention
    attn_e<<<NN/4, 256, 0, stream>>>(hfeat, q_star, bidx, e_ws);
    attn_ms<<<128, 256, 0, stream>>>(e_ws, seg, a_ws, r_ws);
    attn_r<<<(NN + 255)/256, 256, 0, stream>>>(hfeat, a_ws, bidx, r_ws);
    attn_fin<<<128, 256, 0, stream>>>(r_ws, q_star, xc0);
  }

  final_k<<<128, 128, 0, stream>>>(q_star, outW, outb, (float*)d_out);
}